// Round 10
// baseline (595.554 us; speedup 1.0000x reference)
//
#include <hip/hip_runtime.h>

// MalleConv: all f32.
// Inputs: x(4,32,512,512), pa_w(4,2,32,32,3,3), pa_b(4,2,32),
//         exp_w(320,32,1,1), exp_b(320), pw_w(32,32,1,1), pw_b(32)
// Output: (4,32,512,512) f32

#define BATCH 4
#define NCH 32

__device__ __forceinline__ float fast_tanh(float s) {
  float e = __expf(2.f * s);
  return fmaf(-2.f, __builtin_amdgcn_rcpf(e + 1.f), 1.f);
}

// ---- prep: pa_w (8,co,ci,9)->(8,ci,9,co); exp_w (320,32)->(32,320); pw_w (o,c)->(c,o)
__global__ void prep_kernel(const float* __restrict__ pa_w, const float* __restrict__ exp_w,
                            const float* __restrict__ pw_w, float* __restrict__ wt,
                            float* __restrict__ ewt, float* __restrict__ pwt) {
  int i = blockIdx.x * 256 + threadIdx.x;
  if (i < 73728) {
    int tap = i % 9; int t = i / 9;
    int ci = t & 31; t >>= 5;
    int co = t & 31; int layer = t >> 5;
    wt[((layer * 32 + ci) * 9 + tap) * 32 + co] = pa_w[i];
  } else if (i < 83968) {
    int j = i - 73728; int ci = j & 31; int o = j >> 5;
    ewt[ci * 320 + o] = exp_w[j];
  } else if (i < 84992) {
    int j = i - 83968; int c = j & 31; int o = j >> 5;
    pwt[c * 32 + o] = pw_w[j];
  }
}

// ---- avgpool k=4: (B,C,512,512) -> (B,C,128,128)
__global__ void avgpool4_kernel(const float* __restrict__ x, float* __restrict__ out) {
  int idx = blockIdx.x * 256 + threadIdx.x;
  if (idx >= BATCH * NCH * 128 * 128) return;
  int ow = idx & 127; int t = idx >> 7; int oh = t & 127; int bc = t >> 7;
  const float* src = x + ((size_t)(bc * 512 + oh * 4)) * 512 + ow * 4;
  float s = 0.f;
#pragma unroll
  for (int r = 0; r < 4; r++) {
    float4 v = *reinterpret_cast<const float4*>(src + (size_t)r * 512);
    s += v.x + v.y + v.z + v.w;
  }
  out[idx] = s * 0.0625f;
}

// ---- conv3x3 (same padding), C=32->NCO per block, optional leaky-relu, optional residual.
template <int HS, int NCO, bool RELU, bool RES>
__global__ __launch_bounds__(256) void conv3x3_kernel(
    const float* __restrict__ in, const float* __restrict__ wt,
    const float* __restrict__ bias, const float* __restrict__ res,
    float* __restrict__ out) {
  constexpr int TILES = HS / 16;
  constexpr int GROUPS = 32 / NCO;
  __shared__ float s_in[32][18][18];
  int blk = blockIdx.x;
  int g = blk % GROUPS; int rest = blk / GROUPS;
  int b = rest / (TILES * TILES); int t = rest % (TILES * TILES);
  int ty = t / TILES, tx = t % TILES;
  int tid = threadIdx.x;
  int og = g * NCO;
  int gx0 = tx * 16 - 1, gy0 = ty * 16 - 1;
  const float* inb = in + (size_t)b * 32 * HS * HS;

  for (int i = tid; i < 32 * 18 * 18; i += 256) {
    int ci = i / 324; int r = i - ci * 324;
    int row = r / 18; int col = r - row * 18;
    int gy = gy0 + row, gx = gx0 + col;
    float v = 0.f;
    if (gy >= 0 && gy < HS && gx >= 0 && gx < HS)
      v = inb[((size_t)ci * HS + gy) * HS + gx];
    s_in[ci][row][col] = v;
  }
  __syncthreads();

  int px = tid & 15, py = tid >> 4;
  float acc[NCO];
#pragma unroll
  for (int o = 0; o < NCO; o++) acc[o] = bias[og + o];

  for (int ci = 0; ci < 32; ci++) {
    float v[9];
#pragma unroll
    for (int di = 0; di < 3; di++)
#pragma unroll
      for (int dj = 0; dj < 3; dj++)
        v[di * 3 + dj] = s_in[ci][py + di][px + dj];
#pragma unroll
    for (int tap = 0; tap < 9; tap++) {
      const float* wrow = wt + (ci * 9 + tap) * 32 + og;
#pragma unroll
      for (int o = 0; o < NCO; o++)
        acc[o] = fmaf(v[tap], wrow[o], acc[o]);
    }
  }

  int gy = ty * 16 + py, gx = tx * 16 + px;
#pragma unroll
  for (int o = 0; o < NCO; o++) {
    float r2 = acc[o];
    if (RELU) r2 = r2 > 0.f ? r2 : 0.01f * r2;
    size_t oi = (((size_t)b * 32 + og + o) * HS + gy) * HS + gx;
    if (RES) r2 += res[oi];
    out[oi] = r2;
  }
}

// ---- both @64 predictors + inline avgpool2 (known-correct from R8).
__global__ __launch_bounds__(256, 1) void pred64x2_kernel(
    const float* __restrict__ fin, const float* __restrict__ wt,
    const float* __restrict__ pa_b, float* __restrict__ feat1) {
  __shared__ float s_f1[32][16][16];
  __shared__ float s_c1[32][14][14];
  __shared__ float s_o3[32][12][12];
  __shared__ float s_c2[32][10][10];
  int blk = blockIdx.x;
  int txz = blk & 7, tyz = (blk >> 3) & 7, b = blk >> 6;
  int r0 = tyz * 8, c0 = txz * 8;
  int tid = threadIdx.x;

  for (int v = tid; v < 8192; v += 256) {
    int ci = v >> 8; int r = (v >> 4) & 15; int cl = v & 15;
    int fy = r0 - 4 + r, fx = c0 - 4 + cl;
    float s = 0.f;
    if (fy >= 0 && fy < 64 && fx >= 0 && fx < 64) {
      const float* sp = fin + (((size_t)b * 32 + ci) * 128 + fy * 2) * 128 + fx * 2;
      float2 a = *reinterpret_cast<const float2*>(sp);
      float2 bb = *reinterpret_cast<const float2*>(sp + 128);
      s = (a.x + a.y + bb.x + bb.y) * 0.25f;
    }
    s_f1[ci][r][cl] = s;
  }
  __syncthreads();

  const float* w4 = wt + 4 * 9216;
  for (int j = tid; j < 392; j += 256) {
    int pos = j >> 1, half = j & 1;
    int pr = pos / 14, pc = pos - pr * 14;
    int fy = r0 - 3 + pr, fx = c0 - 3 + pc;
    bool inb = (fy >= 0 && fy < 64 && fx >= 0 && fx < 64);
    int og = half * 16;
    float acc[16];
#pragma unroll
    for (int o = 0; o < 16; o++) acc[o] = pa_b[128 + og + o];
    for (int ci = 0; ci < 32; ci++) {
      float v[9];
#pragma unroll
      for (int di = 0; di < 3; di++)
#pragma unroll
        for (int dj = 0; dj < 3; dj++)
          v[di * 3 + dj] = s_f1[ci][pr + di][pc + dj];
#pragma unroll
      for (int tap = 0; tap < 9; tap++) {
        const float* wrow = w4 + (ci * 9 + tap) * 32 + og;
#pragma unroll
        for (int o = 0; o < 16; o++)
          acc[o] = fmaf(v[tap], wrow[o], acc[o]);
      }
    }
#pragma unroll
    for (int o = 0; o < 16; o++) {
      float r2 = acc[o];
      s_c1[og + o][pr][pc] = inb ? (r2 > 0.f ? r2 : 0.01f * r2) : 0.f;
    }
  }
  __syncthreads();

  const float* w5 = wt + 5 * 9216;
  for (int j = tid; j < 288; j += 256) {
    int pos = j >> 1, half = j & 1;
    int qr = pos / 12, qc = pos - qr * 12;
    int fy = r0 - 2 + qr, fx = c0 - 2 + qc;
    bool inb = (fy >= 0 && fy < 64 && fx >= 0 && fx < 64);
    int og = half * 16;
    float acc[16];
#pragma unroll
    for (int o = 0; o < 16; o++) acc[o] = pa_b[160 + og + o];
    for (int ci = 0; ci < 32; ci++) {
      float v[9];
#pragma unroll
      for (int di = 0; di < 3; di++)
#pragma unroll
        for (int dj = 0; dj < 3; dj++)
          v[di * 3 + dj] = s_c1[ci][qr + di][qc + dj];
#pragma unroll
      for (int tap = 0; tap < 9; tap++) {
        const float* wrow = w5 + (ci * 9 + tap) * 32 + og;
#pragma unroll
        for (int o = 0; o < 16; o++)
          acc[o] = fmaf(v[tap], wrow[o], acc[o]);
      }
    }
#pragma unroll
    for (int o = 0; o < 16; o++)
      s_o3[og + o][qr][qc] = inb ? (acc[o] + s_f1[og + o][qr + 2][qc + 2]) : 0.f;
  }
  __syncthreads();

  const float* w6 = wt + 6 * 9216;
  for (int j = tid; j < 200; j += 256) {
    int pos = j >> 1, half = j & 1;
    int ur = pos / 10, uc = pos - ur * 10;
    int fy = r0 - 1 + ur, fx = c0 - 1 + uc;
    bool inb = (fy >= 0 && fy < 64 && fx >= 0 && fx < 64);
    int og = half * 16;
    float acc[16];
#pragma unroll
    for (int o = 0; o < 16; o++) acc[o] = pa_b[192 + og + o];
    for (int ci = 0; ci < 32; ci++) {
      float v[9];
#pragma unroll
      for (int di = 0; di < 3; di++)
#pragma unroll
        for (int dj = 0; dj < 3; dj++)
          v[di * 3 + dj] = s_o3[ci][ur + di][uc + dj];
#pragma unroll
      for (int tap = 0; tap < 9; tap++) {
        const float* wrow = w6 + (ci * 9 + tap) * 32 + og;
#pragma unroll
        for (int o = 0; o < 16; o++)
          acc[o] = fmaf(v[tap], wrow[o], acc[o]);
      }
    }
#pragma unroll
    for (int o = 0; o < 16; o++) {
      float r2 = acc[o];
      s_c2[og + o][ur][uc] = inb ? (r2 > 0.f ? r2 : 0.01f * r2) : 0.f;
    }
  }
  __syncthreads();

  const float* w7 = wt + 7 * 9216;
  {
    int j = tid;
    int pos = j >> 2, q = j & 3;
    int vr = pos / 8, vc = pos - vr * 8;
    int og = q * 8;
    float acc[8];
#pragma unroll
    for (int o = 0; o < 8; o++) acc[o] = pa_b[224 + og + o];
    for (int ci = 0; ci < 32; ci++) {
      float v[9];
#pragma unroll
      for (int di = 0; di < 3; di++)
#pragma unroll
        for (int dj = 0; dj < 3; dj++)
          v[di * 3 + dj] = s_c2[ci][vr + di][vc + dj];
#pragma unroll
      for (int tap = 0; tap < 9; tap++) {
        const float* wrow = w7 + (ci * 9 + tap) * 32 + og;
#pragma unroll
        for (int o = 0; o < 8; o++)
          acc[o] = fmaf(v[tap], wrow[o], acc[o]);
      }
    }
#pragma unroll
    for (int o = 0; o < 8; o++) {
      float r2 = acc[o] + s_o3[og + o][vr + 2][vc + 2];
      feat1[(((size_t)b * 32 + og + o) * 64 + r0 + vr) * 64 + c0 + vc] = r2;
    }
  }
}

// ---- expander 1x1 (32->320) + fast tanh. wmap layout: (B, Hb, 320, Wb).
__global__ __launch_bounds__(256) void expander_kernel(
    const float* __restrict__ feat, const float* __restrict__ ewt,
    const float* __restrict__ eb, float* __restrict__ wmap) {
  int idx = blockIdx.x * 256 + threadIdx.x;  // 1,310,720
  int wq = idx & 15; int t = idx >> 4;
  int o = t % 320; int rest = t / 320;
  int hb = rest & 63; int b = rest >> 6;
  const float* fp = feat + (size_t)b * 131072 + hb * 64 + wq * 4;
  float s0 = eb[o];
  float s1 = s0, s2 = s0, s3 = s0;
#pragma unroll 8
  for (int ci = 0; ci < 32; ci++) {
    float4 f = *reinterpret_cast<const float4*>(fp + (size_t)ci * 4096);
    float wv = ewt[ci * 320 + o];
    s0 = fmaf(f.x, wv, s0); s1 = fmaf(f.y, wv, s1);
    s2 = fmaf(f.z, wv, s2); s3 = fmaf(f.w, wv, s3);
  }
  float4 r;
  r.x = fast_tanh(s0); r.y = fast_tanh(s1);
  r.z = fast_tanh(s2); r.w = fast_tanh(s3);
  *reinterpret_cast<float4*>(wmap + (size_t)((b * 64 + hb) * 320 + o) * 64 + wq * 4) = r;
}

// ---- fused flying conv + final 1x1 (v3, half-batch per dispatch for profiling
// visibility). Grid: 1024 blocks = 2 batches x 64 hb x 8 wtile.
__global__ __launch_bounds__(256, 4) void fused_fly_pw_kernel(
    const float* __restrict__ x, const float* __restrict__ wmap,
    const float* __restrict__ pwt, const float* __restrict__ pw_b,
    float* __restrict__ out, int b0) {
  __shared__ float s_w[8][322];
  __shared__ float s_x[8][10][68];
  int blk = blockIdx.x;
  int wtile = blk & 7; int t = blk >> 3; int hb = t & 63; int b = b0 + (t >> 6);
  int tid = threadIdx.x;

  const float* wsrc = wmap + (size_t)(b * 64 + hb) * 320 * 64 + wtile * 8;
#pragma unroll
  for (int j = 0; j < 10; j++) {
    int idx = j * 256 + tid;
    int tap = idx >> 3, wb8 = idx & 7;
    s_w[wb8][tap] = wsrc[(size_t)tap * 64 + wb8];
  }

  int cp = tid & 31, row = tid >> 5;
  int h = hb * 8 + row;
  int w0 = wtile * 64 + cp * 2;
  int wbl = cp >> 2;
  int h0 = hb * 8;
  int gc0 = wtile * 64 - 1;
  const float* xb = x + (size_t)b * 32 * 262144;

  float2 acc[32];
#pragma unroll
  for (int o = 0; o < 32; o++) {
    float bv = pw_b[o];
    acc[o].x = bv; acc[o].y = bv;
  }

  for (int g = 0; g < 4; g++) {
    __syncthreads();
    const float* xg = xb + (size_t)(g * 8) * 262144;
    for (int e = tid; e < 5280; e += 256) {
      int ch = e / 660; int r2 = e - ch * 660;
      int rr = r2 / 66; int cl = r2 - rr * 66;
      int gy = h0 - 1 + rr, gx = gc0 + cl;
      float v = 0.f;
      if (gy >= 0 && gy < 512 && gx >= 0 && gx < 512)
        v = xg[(size_t)ch * 262144 + (size_t)gy * 512 + gx];
      s_x[ch][rr][cl] = v;
    }
    __syncthreads();

#pragma unroll
    for (int c8 = 0; c8 < 8; c8++) {
      int c = g * 8 + c8;
      const float2* wr2 = reinterpret_cast<const float2*>(&s_w[wbl][c * 10]);
      float2 w01 = wr2[0], w23 = wr2[1], w45 = wr2[2], w67 = wr2[3], w89 = wr2[4];
      float wv[9];
      wv[0] = w01.x; wv[1] = w01.y; wv[2] = w23.x;
      wv[3] = w23.y; wv[4] = w45.x; wv[5] = w45.y;
      wv[6] = w67.x; wv[7] = w67.y; wv[8] = w89.x;
      float fly0 = w89.y, fly1 = w89.y;

#pragma unroll
      for (int di = 0; di < 3; di++) {
        const float2* rp = reinterpret_cast<const float2*>(&s_x[c8][row + di][cp * 2]);
        float2 a = rp[0], bb = rp[1];
        float wa = wv[di * 3 + 0], wb_ = wv[di * 3 + 1], wc = wv[di * 3 + 2];
        fly0 = fmaf(a.x, wa, fly0); fly0 = fmaf(a.y, wb_, fly0); fly0 = fmaf(bb.x, wc, fly0);
        fly1 = fmaf(a.y, wa, fly1); fly1 = fmaf(bb.x, wb_, fly1); fly1 = fmaf(bb.y, wc, fly1);
      }
      const float* prow = pwt + c * 32;
#pragma unroll
      for (int o = 0; o < 32; o++) {
        float pw = prow[o];
        acc[o].x = fmaf(fly0, pw, acc[o].x);
        acc[o].y = fmaf(fly1, pw, acc[o].y);
      }
    }
  }
  float* ob = out + (size_t)b * 32 * 262144 + (size_t)h * 512 + w0;
#pragma unroll
  for (int o = 0; o < 32; o++)
    *reinterpret_cast<float2*>(ob + (size_t)o * 262144) = acc[o];
}

extern "C" void kernel_launch(void* const* d_in, const int* in_sizes, int n_in,
                              void* d_out, int out_size, void* d_ws, size_t ws_size,
                              hipStream_t stream) {
  const float* x     = (const float*)d_in[0];
  const float* pa_w  = (const float*)d_in[1];
  const float* pa_b  = (const float*)d_in[2];
  const float* exp_w = (const float*)d_in[3];
  const float* exp_b = (const float*)d_in[4];
  const float* pw_w  = (const float*)d_in[5];
  const float* pw_b  = (const float*)d_in[6];
  float* out = (float*)d_out;
  float* ws  = (float*)d_ws;

  float* feat0 = ws;                 // 2,097,152
  float* tmpA  = feat0 + 2097152;    // 2,097,152
  float* feat1 = tmpA + 2097152;     // 524,288
  float* wmap  = feat1 + 524288;     // 5,242,880
  float* wt    = wmap + 5242880;     // 73,728
  float* ewt   = wt + 73728;         // 10,240
  float* pwt   = ewt + 10240;        // 1,024

  hipLaunchKernelGGL(prep_kernel, dim3(332), dim3(256), 0, stream, pa_w, exp_w, pw_w, wt, ewt, pwt);
  hipLaunchKernelGGL(avgpool4_kernel, dim3(8192), dim3(256), 0, stream, x, feat0);

  // predictors @128: 8 co per block -> 1024 blocks
  for (int i = 0; i < 2; i++) {
    const float* w1 = wt + (size_t)(i * 2 + 0) * 9216;
    const float* b1 = pa_b + (i * 2 + 0) * 32;
    const float* w2 = wt + (size_t)(i * 2 + 1) * 9216;
    const float* b2 = pa_b + (i * 2 + 1) * 32;
    hipLaunchKernelGGL((conv3x3_kernel<128, 8, true, false>), dim3(1024), dim3(256), 0, stream,
                       feat0, w1, b1, nullptr, tmpA);
    hipLaunchKernelGGL((conv3x3_kernel<128, 8, false, true>), dim3(1024), dim3(256), 0, stream,
                       tmpA, w2, b2, feat0, feat0);
  }

  // both @64 predictors + avgpool2 in one dispatch
  hipLaunchKernelGGL(pred64x2_kernel, dim3(256), dim3(256), 0, stream, feat0, wt, pa_b, feat1);

  hipLaunchKernelGGL(expander_kernel, dim3(5120), dim3(256), 0, stream, feat1, ewt, exp_b, wmap);

  hipLaunchKernelGGL(fused_fly_pw_kernel, dim3(1024), dim3(256), 0, stream,
                     x, wmap, pwt, pw_b, out, 0);
  hipLaunchKernelGGL(fused_fly_pw_kernel, dim3(1024), dim3(256), 0, stream,
                     x, wmap, pwt, pw_b, out, 2);
}

// Round 11
// 380.381 us; speedup vs baseline: 1.5657x; 1.5657x over previous
//
#include <hip/hip_runtime.h>

// MalleConv: all f32. Head feature maps stored PADDED (zero halo) so conv3x3
// needs no bounds checks and no LDS staging.
// feat0p/tmpAp: (4,32,130,136) stride 136, interior at [row+1][col+4], CS=17680
// feat1p/tmpBp: (4,32,66,72)   stride 72,  interior at [row+1][col+4], CS=4752
// Inputs: x(4,32,512,512), pa_w(4,2,32,32,3,3), pa_b(4,2,32),
//         exp_w(320,32,1,1), exp_b(320), pw_w(32,32,1,1), pw_b(32)

#define BATCH 4
#define NCH 32
#define CS128 17680
#define SP128 136
#define CS64 4752
#define SP64 72

__device__ __forceinline__ float fast_tanh(float s) {
  float e = __expf(2.f * s);
  return fmaf(-2.f, __builtin_amdgcn_rcpf(e + 1.f), 1.f);
}

// ---- zero padded head buffers (5,742,592 floats = 1,435,648 float4)
__global__ void zero_kernel(float* __restrict__ p) {
  int i = blockIdx.x * 256 + threadIdx.x;  // 5608*256 = 1,435,648
  *reinterpret_cast<float4*>(p + (size_t)i * 4) = make_float4(0.f, 0.f, 0.f, 0.f);
}

// ---- prep: pa_w (8,co,ci,9)->(8,ci,9,co); exp_w (320,32)->(32,320); pw_w (o,c)->(c,o)
__global__ void prep_kernel(const float* __restrict__ pa_w, const float* __restrict__ exp_w,
                            const float* __restrict__ pw_w, float* __restrict__ wt,
                            float* __restrict__ ewt, float* __restrict__ pwt) {
  int i = blockIdx.x * 256 + threadIdx.x;
  if (i < 73728) {
    int tap = i % 9; int t = i / 9;
    int ci = t & 31; t >>= 5;
    int co = t & 31; int layer = t >> 5;
    wt[((layer * 32 + ci) * 9 + tap) * 32 + co] = pa_w[i];
  } else if (i < 83968) {
    int j = i - 73728; int ci = j & 31; int o = j >> 5;
    ewt[ci * 320 + o] = exp_w[j];
  } else if (i < 84992) {
    int j = i - 83968; int c = j & 31; int o = j >> 5;
    pwt[c * 32 + o] = pw_w[j];
  }
}

// ---- avgpool k=4: x(B,C,512,512) -> feat0p interior
__global__ void avgpool4_kernel(const float* __restrict__ x, float* __restrict__ outp) {
  int idx = blockIdx.x * 256 + threadIdx.x;
  if (idx >= BATCH * NCH * 128 * 128) return;
  int ow = idx & 127; int t = idx >> 7; int oh = t & 127; int bc = t >> 7;
  const float* src = x + ((size_t)(bc * 512 + oh * 4)) * 512 + ow * 4;
  float s = 0.f;
#pragma unroll
  for (int r = 0; r < 4; r++) {
    float4 v = *reinterpret_cast<const float4*>(src + (size_t)r * 512);
    s += v.x + v.y + v.z + v.w;
  }
  outp[(size_t)bc * CS128 + (size_t)(oh + 1) * SP128 + ow + 4] = s * 0.0625f;
}

// ---- avgpool k=2: feat0p interior -> feat1p interior
__global__ void avgpool2_kernel(const float* __restrict__ inp, float* __restrict__ outp) {
  int idx = blockIdx.x * 256 + threadIdx.x;
  if (idx >= BATCH * NCH * 64 * 64) return;
  int ow = idx & 63; int t = idx >> 6; int oh = t & 63; int bc = t >> 6;
  const float* sp = inp + (size_t)bc * CS128 + (size_t)(2 * oh + 1) * SP128 + 2 * ow + 4;
  float2 a = *reinterpret_cast<const float2*>(sp);
  float2 b = *reinterpret_cast<const float2*>(sp + SP128);
  outp[(size_t)bc * CS64 + (size_t)(oh + 1) * SP64 + ow + 4] = (a.x + a.y + b.x + b.y) * 0.25f;
}

// ---- conv3x3 direct (padded in/out, no LDS, no bounds checks).
// wt layout (ci,9,co); NCO outputs per block.
template <int HS, int SP, int CS, int NCO, bool RELU, bool RES>
__global__ __launch_bounds__(256) void conv3x3d_kernel(
    const float* __restrict__ in, const float* __restrict__ wt,
    const float* __restrict__ bias, const float* __restrict__ res,
    float* __restrict__ out) {
  constexpr int TILES = HS / 16;
  constexpr int GROUPS = 32 / NCO;
  int blk = blockIdx.x;
  int g = blk % GROUPS; int rest = blk / GROUPS;
  int b = rest / (TILES * TILES); int t = rest % (TILES * TILES);
  int ty = t / TILES, tx = t % TILES;
  int og = g * NCO;
  int px = threadIdx.x & 15, py = threadIdx.x >> 4;
  int gy = ty * 16 + py, gx = tx * 16 + px;
  size_t pix = (size_t)(gy + 1) * SP + gx + 4;
  const float* inb = in + (size_t)b * 32 * CS + pix;

  float acc[NCO];
#pragma unroll
  for (int o = 0; o < NCO; o++) acc[o] = bias[og + o];

  for (int ci = 0; ci < 32; ci++) {
    const float* p = inb + (size_t)ci * CS;
    float v[9];
    v[0] = p[-SP - 1]; v[1] = p[-SP]; v[2] = p[-SP + 1];
    v[3] = p[-1];      v[4] = p[0];   v[5] = p[1];
    v[6] = p[SP - 1];  v[7] = p[SP];  v[8] = p[SP + 1];
    const float* wr = wt + ci * 288 + og;
#pragma unroll
    for (int tap = 0; tap < 9; tap++) {
      const float* wrow = wr + tap * 32;
#pragma unroll
      for (int o = 0; o < NCO; o++)
        acc[o] = fmaf(v[tap], wrow[o], acc[o]);
    }
  }

  float* ob = out + (size_t)b * 32 * CS + (size_t)og * CS + pix;
  const float* rb = RES ? (res + (size_t)b * 32 * CS + (size_t)og * CS + pix) : nullptr;
#pragma unroll
  for (int o = 0; o < NCO; o++) {
    float r2 = acc[o];
    if (RELU) r2 = r2 > 0.f ? r2 : 0.01f * r2;
    if (RES) r2 += rb[(size_t)o * CS];
    ob[(size_t)o * CS] = r2;
  }
}

// ---- expander 1x1 (32->320) + fast tanh, padded feat1p input.
// Thread = (4-px quad, o). wmap layout (B, Hb, 320, Wb).
__global__ __launch_bounds__(256) void expander_kernel(
    const float* __restrict__ feat, const float* __restrict__ ewt,
    const float* __restrict__ eb, float* __restrict__ wmap) {
  int idx = blockIdx.x * 256 + threadIdx.x;  // 1,310,720
  int wq = idx & 15; int t = idx >> 4;
  int o = t % 320; int rest = t / 320;
  int hb = rest & 63; int b = rest >> 6;
  const float* fp = feat + (size_t)b * 32 * CS64 + (size_t)(hb + 1) * SP64 + 4 + wq * 4;
  float s0 = eb[o];
  float s1 = s0, s2 = s0, s3 = s0;
#pragma unroll 8
  for (int ci = 0; ci < 32; ci++) {
    float4 f = *reinterpret_cast<const float4*>(fp + (size_t)ci * CS64);
    float wv = ewt[ci * 320 + o];
    s0 = fmaf(f.x, wv, s0); s1 = fmaf(f.y, wv, s1);
    s2 = fmaf(f.z, wv, s2); s3 = fmaf(f.w, wv, s3);
  }
  float4 r;
  r.x = fast_tanh(s0); r.y = fast_tanh(s1);
  r.z = fast_tanh(s2); r.w = fast_tanh(s3);
  *reinterpret_cast<float4*>(wmap + (size_t)((b * 64 + hb) * 320 + o) * 64 + wq * 4) = r;
}

// ---- fused flying conv + final 1x1 (unchanged from R9/R10; half-batch per dispatch).
__global__ __launch_bounds__(256, 4) void fused_fly_pw_kernel(
    const float* __restrict__ x, const float* __restrict__ wmap,
    const float* __restrict__ pwt, const float* __restrict__ pw_b,
    float* __restrict__ out, int b0) {
  __shared__ float s_w[8][322];
  __shared__ float s_x[8][10][68];
  int blk = blockIdx.x;
  int wtile = blk & 7; int t = blk >> 3; int hb = t & 63; int b = b0 + (t >> 6);
  int tid = threadIdx.x;

  const float* wsrc = wmap + (size_t)(b * 64 + hb) * 320 * 64 + wtile * 8;
#pragma unroll
  for (int j = 0; j < 10; j++) {
    int idx = j * 256 + tid;
    int tap = idx >> 3, wb8 = idx & 7;
    s_w[wb8][tap] = wsrc[(size_t)tap * 64 + wb8];
  }

  int cp = tid & 31, row = tid >> 5;
  int h = hb * 8 + row;
  int w0 = wtile * 64 + cp * 2;
  int wbl = cp >> 2;
  int h0 = hb * 8;
  int gc0 = wtile * 64 - 1;
  const float* xb = x + (size_t)b * 32 * 262144;

  float2 acc[32];
#pragma unroll
  for (int o = 0; o < 32; o++) {
    float bv = pw_b[o];
    acc[o].x = bv; acc[o].y = bv;
  }

  for (int g = 0; g < 4; g++) {
    __syncthreads();
    const float* xg = xb + (size_t)(g * 8) * 262144;
    for (int e = tid; e < 5280; e += 256) {
      int ch = e / 660; int r2 = e - ch * 660;
      int rr = r2 / 66; int cl = r2 - rr * 66;
      int gy = h0 - 1 + rr, gx = gc0 + cl;
      float v = 0.f;
      if (gy >= 0 && gy < 512 && gx >= 0 && gx < 512)
        v = xg[(size_t)ch * 262144 + (size_t)gy * 512 + gx];
      s_x[ch][rr][cl] = v;
    }
    __syncthreads();

#pragma unroll
    for (int c8 = 0; c8 < 8; c8++) {
      int c = g * 8 + c8;
      const float2* wr2 = reinterpret_cast<const float2*>(&s_w[wbl][c * 10]);
      float2 w01 = wr2[0], w23 = wr2[1], w45 = wr2[2], w67 = wr2[3], w89 = wr2[4];
      float wv[9];
      wv[0] = w01.x; wv[1] = w01.y; wv[2] = w23.x;
      wv[3] = w23.y; wv[4] = w45.x; wv[5] = w45.y;
      wv[6] = w67.x; wv[7] = w67.y; wv[8] = w89.x;
      float fly0 = w89.y, fly1 = w89.y;

#pragma unroll
      for (int di = 0; di < 3; di++) {
        const float2* rp = reinterpret_cast<const float2*>(&s_x[c8][row + di][cp * 2]);
        float2 a = rp[0], bb = rp[1];
        float wa = wv[di * 3 + 0], wb_ = wv[di * 3 + 1], wc = wv[di * 3 + 2];
        fly0 = fmaf(a.x, wa, fly0); fly0 = fmaf(a.y, wb_, fly0); fly0 = fmaf(bb.x, wc, fly0);
        fly1 = fmaf(a.y, wa, fly1); fly1 = fmaf(bb.x, wb_, fly1); fly1 = fmaf(bb.y, wc, fly1);
      }
      const float* prow = pwt + c * 32;
#pragma unroll
      for (int o = 0; o < 32; o++) {
        float pw = prow[o];
        acc[o].x = fmaf(fly0, pw, acc[o].x);
        acc[o].y = fmaf(fly1, pw, acc[o].y);
      }
    }
  }
  float* ob = out + (size_t)b * 32 * 262144 + (size_t)h * 512 + w0;
#pragma unroll
  for (int o = 0; o < 32; o++)
    *reinterpret_cast<float2*>(ob + (size_t)o * 262144) = acc[o];
}

extern "C" void kernel_launch(void* const* d_in, const int* in_sizes, int n_in,
                              void* d_out, int out_size, void* d_ws, size_t ws_size,
                              hipStream_t stream) {
  const float* x     = (const float*)d_in[0];
  const float* pa_w  = (const float*)d_in[1];
  const float* pa_b  = (const float*)d_in[2];
  const float* exp_w = (const float*)d_in[3];
  const float* exp_b = (const float*)d_in[4];
  const float* pw_w  = (const float*)d_in[5];
  const float* pw_b  = (const float*)d_in[6];
  float* out = (float*)d_out;
  float* ws  = (float*)d_ws;

  float* feat0p = ws;                    // 4*32*130*136 = 2,263,040
  float* tmpAp  = feat0p + 2263040;      // 2,263,040
  float* feat1p = tmpAp + 2263040;       // 4*32*66*72 = 608,256
  float* wmap   = feat1p + 608256;       // 5,242,880
  float* tmpBp  = wmap;                  // aliases wmap (dead before expander writes)
  float* wt     = wmap + 5242880;        // 73,728
  float* ewt    = wt + 73728;            // 10,240
  float* pwt    = ewt + 10240;           // 1,024

  // zero feat0p..feat1p end + tmpBp region = contiguous 5,742,592 floats
  hipLaunchKernelGGL(zero_kernel, dim3(5608), dim3(256), 0, stream, ws);
  hipLaunchKernelGGL(prep_kernel, dim3(332), dim3(256), 0, stream, pa_w, exp_w, pw_w, wt, ewt, pwt);
  hipLaunchKernelGGL(avgpool4_kernel, dim3(8192), dim3(256), 0, stream, x, feat0p);

  // predictors @128: NCO=8 -> 1024 blocks
  for (int i = 0; i < 2; i++) {
    const float* w1 = wt + (size_t)(i * 2 + 0) * 9216;
    const float* b1 = pa_b + (i * 2 + 0) * 32;
    const float* w2 = wt + (size_t)(i * 2 + 1) * 9216;
    const float* b2 = pa_b + (i * 2 + 1) * 32;
    hipLaunchKernelGGL((conv3x3d_kernel<128, SP128, CS128, 8, true, false>),
                       dim3(1024), dim3(256), 0, stream, feat0p, w1, b1, nullptr, tmpAp);
    hipLaunchKernelGGL((conv3x3d_kernel<128, SP128, CS128, 8, false, true>),
                       dim3(1024), dim3(256), 0, stream, tmpAp, w2, b2, feat0p, feat0p);
  }

  hipLaunchKernelGGL(avgpool2_kernel, dim3(2048), dim3(256), 0, stream, feat0p, feat1p);

  // predictors @64: NCO=4 -> 512 blocks
  for (int i = 2; i < 4; i++) {
    const float* w1 = wt + (size_t)(i * 2 + 0) * 9216;
    const float* b1 = pa_b + (i * 2 + 0) * 32;
    const float* w2 = wt + (size_t)(i * 2 + 1) * 9216;
    const float* b2 = pa_b + (i * 2 + 1) * 32;
    hipLaunchKernelGGL((conv3x3d_kernel<64, SP64, CS64, 4, true, false>),
                       dim3(512), dim3(256), 0, stream, feat1p, w1, b1, nullptr, tmpBp);
    hipLaunchKernelGGL((conv3x3d_kernel<64, SP64, CS64, 4, false, true>),
                       dim3(512), dim3(256), 0, stream, tmpBp, w2, b2, feat1p, feat1p);
  }

  hipLaunchKernelGGL(expander_kernel, dim3(5120), dim3(256), 0, stream, feat1p, ewt, exp_b, wmap);

  hipLaunchKernelGGL(fused_fly_pw_kernel, dim3(1024), dim3(256), 0, stream,
                     x, wmap, pwt, pw_b, out, 0);
  hipLaunchKernelGGL(fused_fly_pw_kernel, dim3(1024), dim3(256), 0, stream,
                     x, wmap, pwt, pw_b, out, 2);
}